// Round 4
// 710.002 us; speedup vs baseline: 1.0683x; 1.0683x over previous
//
#include <hip/hip_runtime.h>
#include <cmath>

#define BB 2
#define SS_ 2048
#define EE 1024
#define CC 16

typedef __attribute__((ext_vector_type(8))) short short8v;
typedef __attribute__((ext_vector_type(4))) float floatx4;

__device__ __forceinline__ void split4(const float4 v, short4& h, short4& l)
{
    unsigned ux = __float_as_uint(v.x), uy = __float_as_uint(v.y);
    unsigned uz = __float_as_uint(v.z), uw = __float_as_uint(v.w);
    h.x = (short)(ux >> 16); h.y = (short)(uy >> 16);
    h.z = (short)(uz >> 16); h.w = (short)(uw >> 16);
    float lx = v.x - __uint_as_float(ux & 0xFFFF0000u);
    float ly = v.y - __uint_as_float(uy & 0xFFFF0000u);
    float lz = v.z - __uint_as_float(uz & 0xFFFF0000u);
    float lw = v.w - __uint_as_float(uw & 0xFFFF0000u);
    l.x = (short)(__float_as_uint(lx) >> 16);
    l.y = (short)(__float_as_uint(ly) >> 16);
    l.z = (short)(__float_as_uint(lz) >> 16);
    l.w = (short)(__float_as_uint(lw) >> 16);
}

__device__ __forceinline__ void split1(float v, short& h, short& l)
{
    unsigned u = __float_as_uint(v);
    h = (short)(u >> 16);
    float rm = v - __uint_as_float(u & 0xFFFF0000u);
    l = (short)(__float_as_uint(rm) >> 16);
}

__device__ __forceinline__ void split4s(float a, float b, float c, float d,
                                        short4& h, short4& l)
{
    split1(a, h.x, l.x); split1(b, h.y, l.y);
    split1(c, h.z, l.z); split1(d, h.w, l.w);
}

__device__ __forceinline__ void split3_1(float v, short& x1, short& x2, short& x3)
{
    unsigned u = __float_as_uint(v);
    x1 = (short)(u >> 16);
    float r1 = v - __uint_as_float(u & 0xFFFF0000u);
    unsigned u2 = __float_as_uint(r1);
    x2 = (short)(u2 >> 16);
    float r2 = r1 - __uint_as_float(u2 & 0xFFFF0000u);
    x3 = (short)(__float_as_uint(r2) >> 16);
}

__device__ __forceinline__ void split3s(float a, float b, float c, float d,
                                        short4& h1, short4& h2, short4& h3)
{
    split3_1(a, h1.x, h2.x, h3.x); split3_1(b, h1.y, h2.y, h3.y);
    split3_1(c, h1.z, h2.z, h3.z); split3_1(d, h1.w, h2.w, h3.w);
}

__device__ __forceinline__ short4 neg4(short4 a)
{
    short4 r;
    r.x = (short)(a.x ^ (short)0x8000); r.y = (short)(a.y ^ (short)0x8000);
    r.z = (short)(a.z ^ (short)0x8000); r.w = (short)(a.w ^ (short)0x8000);
    return r;
}

__device__ __forceinline__ short8v pack8(short4 a, short4 b)
{
    short8v r;
    r[0] = a.x; r[1] = a.y; r[2] = a.z; r[3] = a.w;
    r[4] = b.x; r[5] = b.y; r[6] = b.z; r[7] = b.w;
    return r;
}

__device__ __forceinline__ short8v negbf(short8v x)
{
    int4 t = *(int4*)&x;
    t.x ^= 0x80008000; t.y ^= 0x80008000;
    t.z ^= 0x80008000; t.w ^= 0x80008000;
    return *(short8v*)&t;
}

// ---------------------------------------------------------------------------
// Split-bf16 MFMA GEMM, K-split + atomic epilogue: C += alpha * A @ B^T
// ---------------------------------------------------------------------------
#define BM 128
#define BN 128
#define BK 32
#define LDP 40

__launch_bounds__(256, 2)
__global__ void gemm_at(const float* __restrict__ A, const float* __restrict__ Bsrc,
                        float* __restrict__ C,
                        int K, int lda, int ldb, int ldc,
                        long sA, long sB, long sC, float alpha, int KS)
{
    __shared__ short sAh[BM * LDP], sAl[BM * LDP], sBh[BN * LDP], sBl[BN * LDP];
    const int z = blockIdx.z;
    const int bz = z / KS, ks = z % KS;
    const int klen = K / KS, kbase = ks * klen;
    A += (size_t)bz * sA; Bsrc += (size_t)bz * sB; C += (size_t)bz * sC;
    const int tid = threadIdx.x;
    const int m0 = blockIdx.y * BM, n0 = blockIdx.x * BN;

    const int lr0 = tid >> 3;
    const int kc0 = (tid & 7) * 4;
    const float* pa = A + (size_t)(m0 + lr0) * lda + kbase + kc0;
    const float* pb = Bsrc + (size_t)(n0 + lr0) * ldb + kbase + kc0;

    float4 ra[4], rb[4];
    #pragma unroll
    for (int c = 0; c < 4; ++c) {
        ra[c] = *(const float4*)(pa + (size_t)c * 32 * lda);
        rb[c] = *(const float4*)(pb + (size_t)c * 32 * ldb);
    }

    const int lane = tid & 63, wid = tid >> 6;
    const int wm = wid >> 1, wn = wid & 1;
    const int lr = lane & 15, qd = lane >> 4;
    const int arow = wm * 64 + lr;
    const int brow = wn * 64 + lr;
    const int koff = qd * 8;

    floatx4 acc[4][4];
    #pragma unroll
    for (int i = 0; i < 4; ++i)
        #pragma unroll
        for (int j = 0; j < 4; ++j)
            acc[i][j] = (floatx4){0.f, 0.f, 0.f, 0.f};

    for (int kt = 0; kt < klen; kt += BK) {
        __syncthreads();
        #pragma unroll
        for (int c = 0; c < 4; ++c) {
            const int row = lr0 + c * 32;
            short4 h, l;
            split4(ra[c], h, l);
            *(short4*)&sAh[row * LDP + kc0] = h;
            *(short4*)&sAl[row * LDP + kc0] = l;
            split4(rb[c], h, l);
            *(short4*)&sBh[row * LDP + kc0] = h;
            *(short4*)&sBl[row * LDP + kc0] = l;
        }
        __syncthreads();
        if (kt + BK < klen) {
            pa += BK; pb += BK;
            #pragma unroll
            for (int c = 0; c < 4; ++c) {
                ra[c] = *(const float4*)(pa + (size_t)c * 32 * lda);
                rb[c] = *(const float4*)(pb + (size_t)c * 32 * ldb);
            }
        }
        short8v ah[4], al[4], bh[4], bl[4];
        #pragma unroll
        for (int i = 0; i < 4; ++i) {
            ah[i] = *(const short8v*)&sAh[(arow + i * 16) * LDP + koff];
            al[i] = *(const short8v*)&sAl[(arow + i * 16) * LDP + koff];
            bh[i] = *(const short8v*)&sBh[(brow + i * 16) * LDP + koff];
            bl[i] = *(const short8v*)&sBl[(brow + i * 16) * LDP + koff];
        }
        #pragma unroll
        for (int i = 0; i < 4; ++i)
            #pragma unroll
            for (int j = 0; j < 4; ++j)
                acc[i][j] = __builtin_amdgcn_mfma_f32_16x16x32_bf16(ah[i], bh[j], acc[i][j], 0, 0, 0);
        #pragma unroll
        for (int i = 0; i < 4; ++i)
            #pragma unroll
            for (int j = 0; j < 4; ++j)
                acc[i][j] = __builtin_amdgcn_mfma_f32_16x16x32_bf16(ah[i], bl[j], acc[i][j], 0, 0, 0);
        #pragma unroll
        for (int i = 0; i < 4; ++i)
            #pragma unroll
            for (int j = 0; j < 4; ++j)
                acc[i][j] = __builtin_amdgcn_mfma_f32_16x16x32_bf16(al[i], bh[j], acc[i][j], 0, 0, 0);
    }

    #pragma unroll
    for (int i = 0; i < 4; ++i) {
        const int mbase = m0 + wm * 64 + i * 16 + qd * 4;
        #pragma unroll
        for (int j = 0; j < 4; ++j) {
            const int n = n0 + wn * 64 + j * 16 + lr;
            #pragma unroll
            for (int r = 0; r < 4; ++r)
                atomicAdd(&C[(size_t)(mbase + r) * ldc + n], alpha * acc[i][j][r]);
        }
    }
}

// ---------------------------------------------------------------------------
// Tall-skinny bf16x3 MFMA: C += alpha * A @ B. A (M,K) fp32, B (K,NT) fp32.
// ---------------------------------------------------------------------------
template<int NT, int MODE>
__launch_bounds__(256, 4)
__global__ void skmfma(const float* __restrict__ A0, const float* __restrict__ A1,
                       const float* __restrict__ B0, const float* __restrict__ B1,
                       float* __restrict__ C0, float* __restrict__ C1,
                       int K, int lda, int ldb, int ldc,
                       long sA, long sB, long sC, float alpha, int KS)
{
    constexpr int NA = (MODE >= 1) ? 2 : 1;
    constexpr int NB = (MODE == 2) ? 2 : 1;
    constexpr int NACC = (MODE == 1) ? 2 : 1;
    constexpr int CT = NT / 16;
    __shared__ short sAh[NA][64 * 40], sAl[NA][64 * 40];
    __shared__ short sBh[NB][NT * 40], sBl[NB][NT * 40];
    const int z = blockIdx.z;
    const int zb = z / KS, ks = z % KS;
    const int klen = K / KS, kbase = ks * klen;
    const float* Ap[NA]; const float* Bp[NB]; float* Cp[NACC];
    Ap[0] = A0 + (size_t)zb * sA;
    if constexpr (NA == 2) Ap[1] = A1 + (size_t)zb * sA;
    Bp[0] = B0 + (size_t)zb * sB;
    if constexpr (NB == 2) Bp[1] = B1 + (size_t)zb * sB;
    Cp[0] = C0 + (size_t)zb * sC;
    if constexpr (NACC == 2) Cp[1] = C1 + (size_t)zb * sC;

    const int tid = threadIdx.x;
    const int m0 = blockIdx.x * 64;
    const int arow = tid >> 2, akc = (tid & 3) * 8;
    const int lane = tid & 63, w = tid >> 6;
    const int lr = lane & 15, qd = lane >> 4;

    floatx4 acc[NACC][CT];
    #pragma unroll
    for (int s = 0; s < NACC; ++s)
        #pragma unroll
        for (int j = 0; j < CT; ++j)
            acc[s][j] = (floatx4){0.f, 0.f, 0.f, 0.f};

    for (int kc = 0; kc < klen; kc += 32) {
        __syncthreads();
        #pragma unroll
        for (int s = 0; s < NA; ++s) {
            const float* pa = Ap[s] + (size_t)(m0 + arow) * lda + kbase + kc + akc;
            float4 v0 = *(const float4*)pa;
            float4 v1 = *(const float4*)(pa + 4);
            short4 h, l;
            split4(v0, h, l);
            *(short4*)&sAh[s][arow * 40 + akc] = h;
            *(short4*)&sAl[s][arow * 40 + akc] = l;
            split4(v1, h, l);
            *(short4*)&sAh[s][arow * 40 + akc + 4] = h;
            *(short4*)&sAl[s][arow * 40 + akc + 4] = l;
        }
        #pragma unroll
        for (int s = 0; s < NB; ++s) {
            for (int lin = tid; lin < 32 * (NT / 4); lin += 256) {
                int kk = lin / (NT / 4), n4 = (lin % (NT / 4)) * 4;
                float4 v = *(const float4*)(Bp[s] + (size_t)(kbase + kc + kk) * ldb + n4);
                short4 h, l; split4(v, h, l);
                sBh[s][(n4 + 0) * 40 + kk] = h.x; sBh[s][(n4 + 1) * 40 + kk] = h.y;
                sBh[s][(n4 + 2) * 40 + kk] = h.z; sBh[s][(n4 + 3) * 40 + kk] = h.w;
                sBl[s][(n4 + 0) * 40 + kk] = l.x; sBl[s][(n4 + 1) * 40 + kk] = l.y;
                sBl[s][(n4 + 2) * 40 + kk] = l.z; sBl[s][(n4 + 3) * 40 + kk] = l.w;
            }
        }
        __syncthreads();
        short8v ah[NA], alv[NA];
        #pragma unroll
        for (int s = 0; s < NA; ++s) {
            ah[s]  = *(const short8v*)&sAh[s][(w * 16 + lr) * 40 + qd * 8];
            alv[s] = *(const short8v*)&sAl[s][(w * 16 + lr) * 40 + qd * 8];
        }
        short8v bh[NB][CT], bl[NB][CT];
        #pragma unroll
        for (int s = 0; s < NB; ++s)
            #pragma unroll
            for (int j = 0; j < CT; ++j) {
                bh[s][j] = *(const short8v*)&sBh[s][(j * 16 + lr) * 40 + qd * 8];
                bl[s][j] = *(const short8v*)&sBl[s][(j * 16 + lr) * 40 + qd * 8];
            }
        if constexpr (MODE == 0) {
            #pragma unroll
            for (int j = 0; j < CT; ++j) {
                acc[0][j] = __builtin_amdgcn_mfma_f32_16x16x32_bf16(ah[0], bh[0][j], acc[0][j], 0, 0, 0);
                acc[0][j] = __builtin_amdgcn_mfma_f32_16x16x32_bf16(ah[0], bl[0][j], acc[0][j], 0, 0, 0);
                acc[0][j] = __builtin_amdgcn_mfma_f32_16x16x32_bf16(alv[0], bh[0][j], acc[0][j], 0, 0, 0);
            }
        } else if constexpr (MODE == 1) {
            #pragma unroll
            for (int j = 0; j < CT; ++j) {
                acc[0][j] = __builtin_amdgcn_mfma_f32_16x16x32_bf16(ah[0], bh[0][j], acc[0][j], 0, 0, 0);
                acc[0][j] = __builtin_amdgcn_mfma_f32_16x16x32_bf16(ah[0], bl[0][j], acc[0][j], 0, 0, 0);
                acc[0][j] = __builtin_amdgcn_mfma_f32_16x16x32_bf16(alv[0], bh[0][j], acc[0][j], 0, 0, 0);
                acc[1][j] = __builtin_amdgcn_mfma_f32_16x16x32_bf16(ah[1], bh[0][j], acc[1][j], 0, 0, 0);
                acc[1][j] = __builtin_amdgcn_mfma_f32_16x16x32_bf16(ah[1], bl[0][j], acc[1][j], 0, 0, 0);
                acc[1][j] = __builtin_amdgcn_mfma_f32_16x16x32_bf16(alv[1], bh[0][j], acc[1][j], 0, 0, 0);
            }
        } else {
            #pragma unroll
            for (int j = 0; j < CT; ++j) {
                acc[0][j] = __builtin_amdgcn_mfma_f32_16x16x32_bf16(ah[0], bh[0][j], acc[0][j], 0, 0, 0);
                acc[0][j] = __builtin_amdgcn_mfma_f32_16x16x32_bf16(ah[0], bl[0][j], acc[0][j], 0, 0, 0);
                acc[0][j] = __builtin_amdgcn_mfma_f32_16x16x32_bf16(alv[0], bh[0][j], acc[0][j], 0, 0, 0);
                acc[0][j] = __builtin_amdgcn_mfma_f32_16x16x32_bf16(ah[1], bh[1][j], acc[0][j], 0, 0, 0);
                acc[0][j] = __builtin_amdgcn_mfma_f32_16x16x32_bf16(ah[1], bl[1][j], acc[0][j], 0, 0, 0);
                acc[0][j] = __builtin_amdgcn_mfma_f32_16x16x32_bf16(alv[1], bh[1][j], acc[0][j], 0, 0, 0);
            }
        }
    }
    #pragma unroll
    for (int s = 0; s < NACC; ++s)
        #pragma unroll
        for (int j = 0; j < CT; ++j) {
            const int n = j * 16 + lr;
            const int mb = m0 + w * 16 + qd * 4;
            #pragma unroll
            for (int r = 0; r < 4; ++r)
                atomicAdd(&Cp[s][(size_t)(mb + r) * ldc + n], alpha * acc[s][j][r]);
        }
}

// ---------------------------------------------------------------------------
// Trig matrices (DFT + DCT in one launch)
// ---------------------------------------------------------------------------
__global__ void gen_trig(float* __restrict__ Cc, float* __restrict__ Sn,
                         float* __restrict__ D, float* __restrict__ I)
{
    size_t idx = (size_t)blockIdx.x * 256 + threadIdx.x;
    if (idx < 4194304) {
        int k = (int)(idx >> 11);
        int n = (int)(idx & 2047);
        int m = (k * n) & 2047;
        float ang = (float)(6.283185307179586 * (double)m / 2048.0);
        Cc[idx] = cosf(ang);
        Sn[idx] = -sinf(ang);
    } else {
        idx -= 4194304;
        int i = (int)(idx >> 11);
        int j = (int)(idx & 2047);
        const float r1 = 0.022097086912079608f;
        const float r2 = 0.03125f;
        const float pif = 3.14159265358979323846f;
        float a  = (pif * (float)i) * (float)(2 * j + 1) / 4096.0f;
        D[idx] = cosf(a) * (i == 0 ? r1 : r2);
        float ai = (pif * (float)j) * (float)(2 * i + 1) / 4096.0f;
        I[idx] = cosf(ai) * (j == 0 ? r1 : r2);
    }
}

// ---------------------------------------------------------------------------
// fw softmax (stored transposed, e-major) + G = (1/32) fw@fw^T. grid 3.
// ---------------------------------------------------------------------------
__launch_bounds__(256)
__global__ void prep_fw_G(const float* __restrict__ F0, const float* __restrict__ F1,
                          const float* __restrict__ F2, float* __restrict__ fwT,
                          float* __restrict__ G)
{
    const int d = blockIdx.x, tid = threadIdx.x;
    const float* Fp = d == 0 ? F0 : (d == 1 ? F1 : F2);
    __shared__ float sf[CC * 1028];
    #pragma unroll
    for (int k = 0; k < 4; ++k) {
        int e = tid + k * 256;
        float v[CC]; float m = -3.4e38f;
        #pragma unroll
        for (int c = 0; c < CC; ++c) { v[c] = Fp[c * EE + e]; m = fmaxf(m, v[c]); }
        float s = 0.f;
        #pragma unroll
        for (int c = 0; c < CC; ++c) { v[c] = expf(v[c] - m); s += v[c]; }
        float inv = 1.f / s;
        #pragma unroll
        for (int c = 0; c < CC; ++c) { v[c] *= inv; sf[c * 1028 + e] = v[c]; }
        #pragma unroll
        for (int j = 0; j < 4; ++j)
            *(float4*)(fwT + d * 16384 + (size_t)e * 16 + j * 4) = *(float4*)&v[j * 4];
    }
    __syncthreads();
    const int a = tid >> 4, b = tid & 15;
    const float4* pa = (const float4*)&sf[a * 1028];
    const float4* pb = (const float4*)&sf[b * 1028];
    float s = 0.f;
    for (int i = 0; i < 256; ++i) {
        float4 x = pa[i], y = pb[i];
        s += x.x * y.x + x.y * y.y + x.z * y.z + x.w * y.w;
    }
    G[d * 256 + a * 16 + b] = s * 0.03125f;
}

__global__ void build_w2(const float* __restrict__ W0, const float* __restrict__ W1,
                         const float* __restrict__ W2_, float* __restrict__ W2cat)
{
    int idx = blockIdx.x * 256 + threadIdx.x;
    if (idx >= 3 * CC * EE * 3) return;
    int d = idx / 49152, r = idx % 49152;
    const float* Wc = d == 0 ? W0 : (d == 1 ? W1 : W2_);
    int c = r / 3072, e = (r % 3072) / 3, k = r % 3;
    W2cat[d * 49152 + e * 48 + c * 3 + k] = Wc[r];
}

__global__ void build_ub2(const float* __restrict__ b0, const float* __restrict__ b1,
                          const float* __restrict__ b2, const float* __restrict__ W2cat,
                          float* __restrict__ ub)
{
    const int d = blockIdx.x, tid = threadIdx.x;
    const float* bp = d == 0 ? b0 : (d == 1 ? b1 : b2);
    __shared__ float red[4][48];
    const int c = tid & 63, sl = tid >> 6;
    float s = 0.f;
    if (c < 48)
        for (int e = sl; e < EE; e += 4)
            s += bp[e] * W2cat[d * 49152 + e * 48 + c];
    if (c < 48) red[sl][c] = s;
    __syncthreads();
    if (tid < 48) ub[d * 48 + tid] = red[0][tid] + red[1][tid] + red[2][tid] + red[3][tid];
}

__launch_bounds__(256)
__global__ void build_yb2(const float* __restrict__ ob, const float* __restrict__ fus_W,
                          const float* __restrict__ fus_b, float* __restrict__ yb)
{
    const int n = blockIdx.x * 4 + (threadIdx.x >> 6);
    const int lane = threadIdx.x & 63;
    float s = 0.f;
    for (int j = lane; j < 3072; j += 64)
        s += ob[j & 1023] * fus_W[(size_t)n * 3072 + j];
    #pragma unroll
    for (int off = 32; off > 0; off >>= 1) s += __shfl_xor(s, off, 64);
    if (lane == 0) yb[n] = s + fus_b[n];
}

// init: [W3cat 0 | Ucat=ub | Tfr,Tfi,Tc,Rf,Rc 0] + Pt 0 + FTb 0 + out=yb
__global__ void init_all(float* __restrict__ zone1, const float* __restrict__ ub,
                         float* __restrict__ Pt, float* __restrict__ FTb,
                         float* __restrict__ out, const float* __restrict__ yb)
{
    size_t idx = (size_t)blockIdx.x * 256 + threadIdx.x;
    const size_t W3N = 147456, UN = 589824, ZN = 720896;
    const size_t Z1 = W3N + UN + ZN;                 // 1458176
    const size_t PTN = 156672, FTN = 3145728, ON = 4194304;
    if (idx < Z1) {
        float v = 0.f;
        if (idx >= W3N && idx < W3N + UN) {
            size_t r = idx - W3N;
            int d = (int)(r / 196608), c = (int)(r % 48);
            v = ub[d * 48 + c];
        }
        zone1[idx] = v;
    } else if (idx < Z1 + PTN) {
        Pt[idx - Z1] = 0.f;
    } else if (idx < Z1 + PTN + FTN) {
        FTb[idx - Z1 - PTN] = 0.f;
    } else if (idx < Z1 + PTN + FTN + ON) {
        size_t r = idx - Z1 - PTN - FTN;
        out[r] = yb[r & 1023];
    }
}

__global__ void ib_append(const float* __restrict__ ib, float* __restrict__ Pt)
{
    int idx = blockIdx.x * 256 + threadIdx.x;
    if (idx >= 9216) return;
    int d = idx / 3072, j = idx % 3072;
    Pt[d * 52224 + j * 17 + 16] = ib[j];
}

__launch_bounds__(256)
__global__ void build_M(const float* __restrict__ Pt, float* __restrict__ Mten)
{
    int blk = blockIdx.x;             // h*9 + l*3 + m
    int h = blk / 9, lm = blk % 9;
    int l = lm / 3, m = lm % 3;
    __shared__ float sQ[64][17], sK[64][17];
    for (int lin = threadIdx.x; lin < 1088; lin += 256) {
        int d = lin / 17, a = lin % 17;
        sQ[d][a] = Pt[l * 52224 + (size_t)(h * 64 + d) * 17 + a];
        sK[d][a] = Pt[m * 52224 + (size_t)(1024 + h * 64 + d) * 17 + a];
    }
    __syncthreads();
    for (int o = threadIdx.x; o < 289; o += 256) {
        int a = o / 17, b = o % 17;
        float s = 0.f;
        for (int d = 0; d < 64; ++d) s += sQ[d][a] * sK[d][b];
        Mten[(size_t)blk * 289 + o] = 0.125f * s;
    }
}

__global__ void transpose_k(const float* __restrict__ X, float* __restrict__ XT,
                            int rows, int cols)
{
    __shared__ float tile[32][33];
    const int lx = threadIdx.x & 31, ly = threadIdx.x >> 5;
    const int r0 = blockIdx.y * 32, c0 = blockIdx.x * 32;
    #pragma unroll
    for (int p = 0; p < 4; ++p)
        tile[ly + p * 8][lx] = X[(size_t)(r0 + ly + p * 8) * cols + c0 + lx];
    __syncthreads();
    #pragma unroll
    for (int p = 0; p < 4; ++p)
        XT[(size_t)(c0 + ly + p * 8) * rows + r0 + lx] = tile[lx][ly + p * 8];
}

__global__ void transpose_wp3(const float* __restrict__ W0, const float* __restrict__ W1,
                              const float* __restrict__ W2, float* __restrict__ WT)
{
    __shared__ float tile[32][33];
    const float* X = blockIdx.z == 0 ? W0 : (blockIdx.z == 1 ? W1 : W2);
    float* T = WT + (size_t)blockIdx.z * 1048576;
    const int lx = threadIdx.x & 31, ly = threadIdx.x >> 5;
    const int r0 = blockIdx.y * 32, c0 = blockIdx.x * 32;
    #pragma unroll
    for (int p = 0; p < 4; ++p)
        tile[ly + p * 8][lx] = X[(size_t)(r0 + ly + p * 8) * 1024 + c0 + lx];
    __syncthreads();
    #pragma unroll
    for (int p = 0; p < 4; ++p)
        T[(size_t)(c0 + ly + p * 8) * 1024 + r0 + lx] = tile[lx][ly + p * 8];
}

// ---------------------------------------------------------------------------
// Full Haar pyramid, one kernel. grid (48/HCG, B).
// ---------------------------------------------------------------------------
#define HCG 4
__launch_bounds__(256)
__global__ void haar_all(const float* __restrict__ U, float* __restrict__ T)
{
    __shared__ float A[2048 * HCG];
    __shared__ float Pp[1024 * HCG];
    const int g = blockIdx.x, b = blockIdx.y, tid = threadIdx.x;
    const float isq = 0.70710678118654752440f;
    for (int lin = tid; lin < 2048; lin += 256)
        *(float4*)&A[lin * 4] = *(const float4*)(U + ((size_t)(b * 2048 + lin)) * 48 + g * HCG);
    __syncthreads();
    float* cur = A; float* nxt = Pp;
    for (int h = 1024; h >= 1; h >>= 1) {
        for (int lin = tid; lin < h * HCG; lin += 256) {
            int i = lin >> 2, c = lin & 3;
            float e = cur[(2 * i) * HCG + c], o = cur[(2 * i + 1) * HCG + c];
            T[((size_t)(b * 2048 + h + i)) * 48 + g * HCG + c] = (e - o) * isq;
            nxt[i * HCG + c] = (e + o) * isq;
        }
        __syncthreads();
        float* t = cur; cur = nxt; nxt = t;
    }
    if (tid < HCG) T[((size_t)(b * 2048)) * 48 + g * HCG + tid] = cur[tid];
}

// ---------------------------------------------------------------------------
// conv collapse + G fold, all 3 domains in one launch. grid (32, B, 3).
// ---------------------------------------------------------------------------
__launch_bounds__(256)
__global__ void conv_all(const float* __restrict__ Tfr, const float* __restrict__ Tfi,
                         const float* __restrict__ Tw, const float* __restrict__ Tc,
                         const float* __restrict__ Gm,
                         const float* __restrict__ bc0, const float* __restrict__ bc1,
                         const float* __restrict__ bc2,
                         float* __restrict__ chFr, float* __restrict__ chFi,
                         float* __restrict__ chW, float* __restrict__ chC,
                         float* __restrict__ QFr, float* __restrict__ QFi,
                         float* __restrict__ QW, float* __restrict__ QC)
{
    const int dom = blockIdx.z;
    const bool cplx = (dom == 0);
    const float* Tre = dom == 0 ? Tfr : (dom == 1 ? Tw : Tc);
    const float* Tim = Tfi;
    const float* G = Gm + dom * 256;
    const float* bc = dom == 0 ? bc0 : (dom == 1 ? bc1 : bc2);
    float* chR = dom == 0 ? chFr : (dom == 1 ? chW : chC);
    float* chI = chFi;
    float* QR = dom == 0 ? QFr : (dom == 1 ? QW : QC);
    float* QI = QFi;

    const int s0 = blockIdx.x * 64, b = blockIdx.y;
    const int tid = threadIdx.x;
    __shared__ float sR[66 * 49];
    __shared__ float sI[66 * 49];
    __shared__ float scr[64 * 17];
    __shared__ float sci[64 * 17];
    __shared__ float sG[256];
    if (tid < 256) sG[tid] = G[tid];
    for (int lin = tid; lin < 66 * 12; lin += 256) {
        int r = lin / 12, c4 = (lin % 12) * 4;
        int srow = s0 - 1 + r;
        float4 v = {0.f, 0.f, 0.f, 0.f}, w = {0.f, 0.f, 0.f, 0.f};
        if (srow >= 0 && srow < 2048) {
            v = *(const float4*)(Tre + ((size_t)(b * 2048 + srow)) * 48 + c4);
            if (cplx) w = *(const float4*)(Tim + ((size_t)(b * 2048 + srow)) * 48 + c4);
        }
        sR[r * 49 + c4] = v.x; sR[r * 49 + c4 + 1] = v.y;
        sR[r * 49 + c4 + 2] = v.z; sR[r * 49 + c4 + 3] = v.w;
        if (cplx) {
            sI[r * 49 + c4] = w.x; sI[r * 49 + c4 + 1] = w.y;
            sI[r * 49 + c4 + 2] = w.z; sI[r * 49 + c4 + 3] = w.w;
        }
    }
    __syncthreads();
    const int row = tid >> 2, ln = tid & 3;
    float ch[4], chi[4];
    #pragma unroll
    for (int j = 0; j < 4; ++j) {
        int c = ln * 4 + j;
        float bcv = bc[c];
        ch[j] = sR[row * 49 + 3 * c] + sR[(row + 1) * 49 + 3 * c + 1]
              + sR[(row + 2) * 49 + 3 * c + 2] + bcv;
        scr[row * 17 + c] = ch[j];
        if (cplx) {
            chi[j] = sI[row * 49 + 3 * c] + sI[(row + 1) * 49 + 3 * c + 1]
                   + sI[(row + 2) * 49 + 3 * c + 2] + bcv;
            sci[row * 17 + c] = chi[j];
        }
    }
    size_t ro = ((size_t)(b * 2048 + s0 + row)) * 16 + ln * 4;
    *(float4*)(chR + ro) = *(float4*)&ch[0];
    if (cplx) *(float4*)(chI + ro) = *(float4*)&chi[0];
    __syncthreads();
    float qp[4] = {}, qpi[4] = {};
    #pragma unroll
    for (int c = 0; c < 16; ++c) {
        float cv = scr[row * 17 + c];
        float cvi = cplx ? sci[row * 17 + c] : 0.f;
        #pragma unroll
        for (int j = 0; j < 4; ++j) {
            float g = sG[c * 16 + ln * 4 + j];
            qp[j] = fmaf(cv, g, qp[j]);
            if (cplx) qpi[j] = fmaf(cvi, g, qpi[j]);
        }
    }
    *(float4*)(QR + ro) = *(float4*)&qp[0];
    if (cplx) *(float4*)(QI + ro) = *(float4*)&qpi[0];
}

// ---------------------------------------------------------------------------
// prep_flash: build split-bf16 operands for the MFMA flash path.
// NOTE: NO extra scale on q — the reference's 1/sqrt(1024) is already folded
// into G (prep_fw_G's 0.03125), so scores = Qp . ch directly (matches the
// round-0 passing VALU flash).
// SPLIT-3 scores (limbs q1,q2,q3 / k1,k2,k3): score rel err ~2^-24.
// Real dom d: Aq row 48sh [q1|q2|q3], Ks row 48sh [k1|k2|k3],
//             Vt[e][t] hi/lo split-2 (transposed V).
// Complex:    AqF row 96sh [q1r|q1i|q2r|q2i|q3r|q3i],
//             BreF [k1r|-k1i|k2r|-k2i|k3r|-k3i],
//             BimF [k1i|k1r|k2i|k2r|k3i|k3r], Vtr/Vti hi/lo.
// grid (8, 2, 3), 256 thr.
// ---------------------------------------------------------------------------
__launch_bounds__(256)
__global__ void prep_flash(const float* __restrict__ QpFr, const float* __restrict__ QpFi,
                           const float* __restrict__ chFr, const float* __restrict__ chFi,
                           const float* __restrict__ QpW, const float* __restrict__ chW,
                           const float* __restrict__ QpC, const float* __restrict__ chC,
                           short* __restrict__ AqF, short* __restrict__ BreF,
                           short* __restrict__ BimF,
                           short* __restrict__ VtFrH, short* __restrict__ VtFrL,
                           short* __restrict__ VtFiH, short* __restrict__ VtFiL,
                           short* __restrict__ AqW, short* __restrict__ KsW,
                           short* __restrict__ VtWH, short* __restrict__ VtWL,
                           short* __restrict__ AqC, short* __restrict__ KsC,
                           short* __restrict__ VtCH, short* __restrict__ VtCL)
{
    const int t0 = blockIdx.x * 256, b = blockIdx.y, dom = blockIdx.z;
    const int tid = threadIdx.x;
    const size_t row = (size_t)b * 2048 + t0 + tid;
    const int e = tid >> 4, ts = (tid & 15) * 16;
    const size_t vo = (size_t)(b * 16 + e) * 2048 + t0 + ts;
    if (dom != 0) {
        const float* Qp = dom == 1 ? QpW : QpC;
        const float* ch = dom == 1 ? chW : chC;
        short* Aq = dom == 1 ? AqW : AqC;
        short* Ks = dom == 1 ? KsW : KsC;
        short* VH = dom == 1 ? VtWH : VtCH;
        short* VL = dom == 1 ? VtWL : VtCL;
        float q[16], k[16];
        #pragma unroll
        for (int j = 0; j < 4; ++j) {
            *(float4*)&q[j * 4] = *(const float4*)(Qp + row * 16 + j * 4);
            *(float4*)&k[j * 4] = *(const float4*)(ch + row * 16 + j * 4);
        }
        #pragma unroll
        for (int j = 0; j < 4; ++j) {
            short4 h1, h2, h3;
            split3s(q[j * 4], q[j * 4 + 1], q[j * 4 + 2], q[j * 4 + 3], h1, h2, h3);
            *(short4*)&Aq[row * 48 + j * 4]      = h1;
            *(short4*)&Aq[row * 48 + 16 + j * 4] = h2;
            *(short4*)&Aq[row * 48 + 32 + j * 4] = h3;
            split3s(k[j * 4], k[j * 4 + 1], k[j * 4 + 2], k[j * 4 + 3], h1, h2, h3);
            *(short4*)&Ks[row * 48 + j * 4]      = h1;
            *(short4*)&Ks[row * 48 + 16 + j * 4] = h2;
            *(short4*)&Ks[row * 48 + 32 + j * 4] = h3;
        }
        // transposed V (split-2; V precision is not score-critical)
        #pragma unroll
        for (int j = 0; j < 4; ++j) {
            float v0 = ch[((size_t)b * 2048 + t0 + ts + j * 4 + 0) * 16 + e];
            float v1 = ch[((size_t)b * 2048 + t0 + ts + j * 4 + 1) * 16 + e];
            float v2 = ch[((size_t)b * 2048 + t0 + ts + j * 4 + 2) * 16 + e];
            float v3 = ch[((size_t)b * 2048 + t0 + ts + j * 4 + 3) * 16 + e];
            short4 h, l; split4s(v0, v1, v2, v3, h, l);
            *(short4*)&VH[vo + j * 4] = h;
            *(short4*)&VL[vo + j * 4] = l;
        }
        return;
    }
    // complex (fourier)
    float qr[16], qi[16], kr[16], ki[16];
    #pragma unroll
    for (int j = 0; j < 4; ++j) {
        *(float4*)&qr[j * 4] = *(const float4*)(QpFr + row * 16 + j * 4);
        *(float4*)&qi[j * 4] = *(const float4*)(QpFi + row * 16 + j * 4);
        *(float4*)&kr[j * 4] = *(const float4*)(chFr + row * 16 + j * 4);
        *(float4*)&ki[j * 4] = *(const float4*)(chFi + row * 16 + j * 4);
    }
    #pragma unroll
    for (int j = 0; j < 4; ++j) {
        short4 q1, q2, q3, p1, p2, p3, r1, r2, r3, s1, s2, s3;
        split3s(qr[j * 4], qr[j * 4 + 1], qr[j * 4 + 2], qr[j * 4 + 3], q1, q2, q3);
        split3s(qi[j * 4], qi[j * 4 + 1], qi[j * 4 + 2], qi[j * 4 + 3], p1, p2, p3);
        split3s(kr[j * 4], kr[j * 4 + 1], kr[j * 4 + 2], kr[j * 4 + 3], r1, r2, r3);
        split3s(ki[j * 4], ki[j * 4 + 1], ki[j * 4 + 2], ki[j * 4 + 3], s1, s2, s3);
        *(short4*)&AqF[row * 96 + j * 4]      = q1;
        *(short4*)&AqF[row * 96 + 16 + j * 4] = p1;
        *(short4*)&AqF[row * 96 + 32 + j * 4] = q2;
        *(short4*)&AqF[row * 96 + 48 + j * 4] = p2;
        *(short4*)&AqF[row * 96 + 64 + j * 4] = q3;
        *(short4*)&AqF[row * 96 + 80 + j * 4] = p3;
        *(short4*)&BreF[row * 96 + j * 4]      = r1;
        *(short4*)&BreF[row * 96 + 16 + j * 4] = neg4(s1);
        *(short4*)&BreF[row * 96 + 32 + j * 4] = r2;
        *(short4*)&BreF[row * 96 + 48 + j * 4] = neg4(s2);
        *(short4*)&BreF[row * 96 + 64 + j * 4] = r3;
        *(short4*)&BreF[row * 96 + 80 + j * 4] = neg4(s3);
        *(short4*)&BimF[row * 96 + j * 4]      = s1;
        *(short4*)&BimF[row * 96 + 16 + j * 4] = r1;
        *(short4*)&BimF[row * 96 + 32 + j * 4] = s2;
        *(short4*)&BimF[row * 96 + 48 + j * 4] = r2;
        *(short4*)&BimF[row * 96 + 64 + j * 4] = s3;
        *(short4*)&BimF[row * 96 + 80 + j * 4] = r3;
    }
    #pragma unroll
    for (int j = 0; j < 4; ++j) {
        float v0 = chFr[((size_t)b * 2048 + t0 + ts + j * 4 + 0) * 16 + e];
        float v1 = chFr[((size_t)b * 2048 + t0 + ts + j * 4 + 1) * 16 + e];
        float v2 = chFr[((size_t)b * 2048 + t0 + ts + j * 4 + 2) * 16 + e];
        float v3 = chFr[((size_t)b * 2048 + t0 + ts + j * 4 + 3) * 16 + e];
        short4 h, l; split4s(v0, v1, v2, v3, h, l);
        *(short4*)&VtFrH[vo + j * 4] = h;
        *(short4*)&VtFrL[vo + j * 4] = l;
        v0 = chFi[((size_t)b * 2048 + t0 + ts + j * 4 + 0) * 16 + e];
        v1 = chFi[((size_t)b * 2048 + t0 + ts + j * 4 + 1) * 16 + e];
        v2 = chFi[((size_t)b * 2048 + t0 + ts + j * 4 + 2) * 16 + e];
        v3 = chFi[((size_t)b * 2048 + t0 + ts + j * 4 + 3) * 16 + e];
        split4s(v0, v1, v2, v3, h, l);
        *(short4*)&VtFiH[vo + j * 4] = h;
        *(short4*)&VtFiL[vo + j * 4] = l;
    }
}

// ---------------------------------------------------------------------------
// Score composition: IDENTICAL MFMA sequences in stats and pv.
// Real (A1=[q1|q2], A2=[q3|q3]; B1=[k1|k1], B2=[k2|k2], B3=[k3|k3], B12=[k1|k2]):
//   S = A1B1 + A1B2 + A1B3 + A2B12  (all limb products except q3k3)
// Complex (Aj=[qjr|qji]; Bj per part):
//   S = A1B1 + A1B2 + A2B1 + A1B3 + A2B2 + A3B1
// ---------------------------------------------------------------------------

// flash_stats: per-row (m, l) partials via MFMA scores.
// grid (32 rowtiles, KS=4 key-splits, 6 slabs), 256 thr = 4 waves x 16 rows.
__launch_bounds__(256)
__global__ void flash_stats(const short* __restrict__ AqF, const short* __restrict__ BreF,
                            const short* __restrict__ AqW, const short* __restrict__ KsW,
                            const short* __restrict__ AqC, const short* __restrict__ KsC,
                            float* __restrict__ Mpart, float* __restrict__ Lpart)
{
    const int z = blockIdx.z, dom = z >> 1, b = z & 1;
    const int tid = threadIdx.x, w = tid >> 6, lane = tid & 63;
    const int lr = lane & 15, qd = lane >> 4;
    const int rowbase = blockIdx.x * 64 + w * 16;
    const int ks = blockIdx.y;
    const size_t qrow = (size_t)b * 2048 + rowbase + lr;
    const floatx4 FZ = {0.f, 0.f, 0.f, 0.f};
    float m[4] = {-3.4e38f, -3.4e38f, -3.4e38f, -3.4e38f};
    float l[4] = {0.f, 0.f, 0.f, 0.f};
    if (dom == 0) {
        const short8v a1 = *(const short8v*)&AqF[qrow * 96 + qd * 8];
        const short8v a2 = *(const short8v*)&AqF[qrow * 96 + 32 + qd * 8];
        const short8v a3 = *(const short8v*)&AqF[qrow * 96 + 64 + qd * 8];
        const short* Bb = BreF + (size_t)b * 2048 * 96;
        for (int s = 0; s < 32; ++s) {
            const short* brow = Bb + (size_t)(ks * 512 + s * 16 + lr) * 96;
            short8v b1 = *(const short8v*)&brow[qd * 8];
            short8v b2 = *(const short8v*)&brow[32 + qd * 8];
            short8v b3 = *(const short8v*)&brow[64 + qd * 8];
            floatx4 sc = __builtin_amdgcn_mfma_f32_16x16x32_bf16(a1, b1, FZ, 0, 0, 0);
            sc = __builtin_amdgcn_mfma_f32_16x16x32_bf16(a1, b2, sc, 0, 0, 0);
            sc = __builtin_amdgcn_mfma_f32_16x16x32_bf16(a2, b1, sc, 0, 0, 0);
            sc = __builtin_amdgcn_mfma_f32_16x16x32_bf16(a1, b3, sc, 0, 0, 0);
            sc = __builtin_amdgcn_mfma_f32_16x16x32_bf16(a2, b2, sc, 0, 0, 0);
            sc = __builtin_amdgcn_mfma_f32_16x16x32_bf16(a3, b1, sc, 0, 0, 0);
            #pragma unroll
            for (int r = 0; r < 4; ++r) {
                float v = sc[r];
                if (v <= m[r]) l[r] += __expf(v - m[r]);
                else { l[r] = l[r] * __expf(m[r] - v) + 1.f; m[r] = v; }
            }
        }
    } else {
        const short* Aq = dom == 1 ? AqW : AqC;
        const short* Ks = dom == 1 ? KsW : KsC;
        const short8v a1 = *(const short8v*)&Aq[qrow * 48 + qd * 8];
        const short8v a2 = *(const short8v*)&Aq[qrow * 48 + 32 + (qd & 1) * 8];
        const short* Kb = Ks + (size_t)b * 2048 * 48;
        const int ko = (qd & 1) * 8;
        for (int s = 0; s < 32; ++s) {
            const short* krow = Kb + (size_t)(ks * 512 + s * 16 + lr) * 48;
            short8v b1  = *(const short8v*)&krow[ko];
            short8v b2  = *(const short8v*)&krow[16 + ko];
            short8v b3  = *(const short8v*)&krow[32 + ko];
            short8v b12 = *(const short8v*)&krow[qd * 8];
            floatx4 sc = __builtin_amdgcn_mfma_f32_16x16x32_bf16(a1, b1, FZ, 0, 0, 0);
            sc = __builtin_amdgcn_mfma_f32_16x16x32_bf16(a1, b2, sc, 0, 0, 0);
            sc = __builtin_amdgcn_mfma_f32_16x16x32_bf16(a1, b3, sc, 0, 0, 0);
            sc = __builtin_amdgcn_mfma_f32_16x16x32_bf16(a2, b12, sc, 0, 0, 0);
            #pragma unroll
            for (int r = 0; r < 4; ++r) {
                float v = sc[r];
                if (v <= m[r]) l[r] += __expf(v - m[r]);
                else { l[r] = l[r] * __expf(m[r] - v) + 1.f; m[r] = v; }
            }
        }
    }
    #pragma unroll
    for (int off = 1; off < 16; off <<= 1) {
        #pragma unroll
        for (int r = 0; r < 4; ++r) {
            float m2 = __shfl_xor(m[r], off, 64);
            float l2 = __shfl_xor(l[r], off, 64);
            float mn = fmaxf(m[r], m2);
            l[r] = l[r] * __expf(m[r] - mn) + l2 * __expf(m2 - mn);
            m[r] = mn;
        }
    }
    if (lr == 0) {
        size_t base = ((size_t)z * 4 + ks) * 2048 + rowbase + qd * 4;
        #pragma unroll
        for (int r = 0; r < 4; ++r) { Mpart[base + r] = m[r]; Lpart[base + r] = l[r]; }
    }
}

// ---------------------------------------------------------------------------
// flash_merge: fold KS=4 partials -> Mrow, 1/l. Also zeroes the O region
// (OFr|OFi|Ow|Oc contiguous, 262144 floats) for the atomic PV pass.
// ---------------------------------------------------------------------------
__global__ void flash_merge(const float* __restrict__ Mpart, const float* __restrict__ Lpart,
                            float* __restrict__ Mrow, float* __restrict__ Linv,
                            float* __restrict__ Ozone)
{
    size_t idx = (size_t)blockIdx.x * 256 + threadIdx.x;
    if (idx < 12288) {
        size_t s = idx >> 11, r = idx & 2047;
        float m = -3.4e38f;
        #pragma unroll
        for (int k = 0; k < 4; ++k) m = fmaxf(m, Mpart[(s * 4 + k) * 2048 + r]);
        float l = 0.f;
        #pragma unroll
        for (int k = 0; k < 4; ++k)
            l += Lpart[(s * 4 + k) * 2048 + r] * __expf(Mpart[(s * 4 + k) * 2048 + r] - m);
        Mrow[idx] = m;
        Linv[idx] = 1.f / l;
    } else if (idx < 12288 + 262144) {
        Ozone[idx - 12288] = 0.f;
    }
}

// ---------------------------------------------------------------------------
// flash_pv: recompute scores (bit-identical to stats), P=exp(sc-M),
// PV via split-bf16 MFMA (P round-trips per-wave LDS D->A layout).
// Atomic-add into O, scaled by 1/l at the end. Same grid as stats.
// ---------------------------------------------------------------------------
__launch_bounds__(256)
__global__ void flash_pv(const short* __restrict__ AqF, const short* __restrict__ BreF,
                         const short* __restrict__ BimF,
                         const short* __restrict__ VtFrH, const short* __restrict__ VtFrL,
                         const short* __restrict__ VtFiH, const short* __restrict__ VtFiL,
                         const short* __restrict__ AqW, const short* __restrict__ KsW,
                         const short* __restrict__ VtWH, const short* __restrict__ VtWL,
                         const short* __restrict__ AqC, const short* __restrict__ KsC,
                         const short* __restrict__ VtCH, const short* __restrict__ VtCL,
                         const float* __restrict__ Mrow, const float* __restrict__ Linv,
                         float* __restrict__ OFr, float* __restrict__ OFi,
                         float* __restrict__ Ow_, float* __restrict__ Oc_)
{
    __shared__ float sP[4][1152];    // per wave: [2][16*36]
    const int z = blockIdx.z, dom = z >> 1, b = z & 1;
    const int tid = threadIdx.x, w = tid >> 6, lane = tid & 63;
    const int lr = lane & 15, qd = lane >> 4;
    const int rowbase = blockIdx.x * 64 + w * 16;
    const int ks = blockIdx.y;
    const size_t qrow = (size_t)b * 2048 + rowbase + lr;
    const floatx4 FZ = {0.f, 0.f, 0.f, 0.f};
    float* P0 = &sP[w][0];
    const float4 m4 = *(const float4*)&Mrow[(size_t)z * 2048 + rowbase + qd * 4];
    const float4 li4 = *(const float4*)&Linv[(size_t)z * 2048 + rowbase + qd * 4];
    const float mA[4] = {m4.x, m4.y, m4.z, m4.w};
    const float liA[4] = {li4.x, li4.y, li4.z, li4.w};

    if (dom != 0) {
        const short* Aq = dom == 1 ? AqW : AqC;
        const short* Ks = dom == 1 ? KsW : KsC;
        const short* VH = dom == 1 ? VtWH : VtCH;
        const short* VL = dom == 1 ? VtWL : VtCL;
        float* O = dom == 1 ? Ow_ : Oc_;
        const short8v a1 = *(const short8v*)&Aq[qrow * 48 + qd * 8];
        const short8v a2 = *(const short8v*)&Aq[qrow * 48 + 32 + (qd & 1) * 8];
        const short* Kb = Ks + (size_t)b * 2048 * 48;
        const short* vhB = VH + (size_t)(b * 16 + lr) * 2048;
        const short* vlB = VL + (size_t)(b * 16 + lr) * 2048;
        const int ko = (qd & 1) * 8;
        floatx4 acc = FZ;
        for (int c = 0; c < 16; ++c) {
            const int tt = ks * 512 + c * 32;
            #pragma unroll
            for (int s2 = 0; s2 < 2; ++s2) {
                const short* krow = Kb + (size_t)(tt + s2 * 16 + lr) * 48;
                short8v b1  = *(const short8v*)&krow[ko];
                short8v b2  = *(const short8v*)&krow[16 + ko];
                short8v b3  = *(const short8v*)&krow[32 + ko];
                short8v b12 = *(const short8v*)&krow[qd * 8];
                floatx4 sc = __builtin_amdgcn_mfma_f32_16x16x32_bf16(a1, b1, FZ, 0, 0, 0);
                sc = __builtin_amdgcn_mfma_f32_16x16x32_bf16(a1, b2, sc, 0, 0, 0);
                sc = __builtin_amdgcn_mfma_f32_16x16x32_bf16(a1, b3, sc, 0, 0, 0);
                sc = __builtin_amdgcn_mfma_f32_16x16x32_bf16(a2, b12, sc, 0, 0, 0);
                #pragma unroll
                for (int r = 0; r < 4; ++r)
                    P0[(qd * 4 + r) * 36 + s2 * 16 + lr] = __expf(sc[r] - mA[r]);
            }
            asm volatile("s_waitcnt lgkmcnt(0)" ::: "memory");
            __builtin_amdgcn_sched_barrier(0);
            float4 p0 = *(const float4*)&P0[lr * 36 + qd * 8];
            float4 p1 = *(const float4*)&P0[lr * 36 + qd * 8 + 4];
            short4 h0, g0, h1, g1;
            split4s(p0.x, p0.y, p0.z, p0.w, h0, g0);
            split4s(p1.x, p1.y, p1.z, p1.w, h1, g1);
            short8v ph = pack8(h0, h1), pl = pack8(g0, g1);
            short8v vh = *(const short8v*)&vhB[tt + qd * 8];
            short8v vl = *(const short8v*)&vlB[tt + qd * 8];
            acc = __builtin_amdgcn_mfma_f32_16x16x32_bf16(ph, vh, acc, 0, 0, 0);
            acc = __builtin_amdgcn_mfma_f32_16x16x32_bf16(ph, vl, acc, 0, 0, 0);
            acc = __builtin_amdgcn_mfma_f32_16x16x32_bf16(pl, vh, acc, 0, 0, 0);
        }
        size_t ob = ((size_t)b * 2048 + rowbase + qd * 4) * 16 + lr;
        #pragma unroll
        for (int r = 0; r < 4; ++r)
            atomicAdd(&O[ob + (size_t)r * 16], acc[r] * liA[r]);
        return;
    }
    // complex
    const short8v a1 = *(const short8v*)&AqF[qrow * 96 + qd * 8];
    const short8v a2 = *(const short8v*)&AqF[qrow * 96 + 32 + qd * 8];
    const short8v a3 = *(const short8v*)&AqF[qrow * 96 + 64 + qd * 8];
    const short* BrB = BreF + (size_t)b * 2048 * 96;
    const short* BiB = BimF + (size_t)b * 2048 * 96;
    const short* vrhB = VtFrH + (size_t)(b * 16 + lr) * 2048;
    const short* vrlB = VtFrL + (size_t)(b * 16 + lr) * 2048;
    const short* vihB = VtFiH + (size_t)(b * 16 + lr) * 2048;
    const short* vilB = VtFiL + (size_t)(b * 16 + lr) * 2048;
    float* PR = P0;
    float* PI = P0 + 576;
    floatx4 accR = FZ, accI = FZ;
    for (int c = 0; c < 16; ++c) {
        const int tt = ks * 512 + c * 32;
        #pragma unroll
        for (int s2 = 0; s2 < 2; ++s2) {
            const short* br = BrB + (size_t)(tt + s2 * 16 + lr) * 96;
            const short* bi = BiB + (size_t)(tt + s2 * 16 + lr) * 96;
            short8v b1r = *(const short8v*)&br[qd * 8];
            short8v b2r = *(const short8v*)&br[32 + qd * 8];
            short8v b3r = *(const short8v*)&br[64 + qd * 8];
            short8v b1i = *(const short8v*)&bi[qd * 8];
            short8v b2i = *(const short8v*)&bi[32 + qd * 8];
            short8v b3i = *(const short8v*)&bi[64 + qd * 8];
            floatx4 sre = __builtin_amdgcn_mfma_f32_16x16x32_bf16(a1, b1r, FZ, 0, 0, 0);
            sre = __builtin_amdgcn_mfma_f32_16x16x32_bf16(a1, b2r, sre, 0, 0, 0);
            sre = __builtin_amdgcn_mfma_f32_16x16x32_bf16(a2, b1r, sre, 0, 0, 0);
            sre = __builtin_amdgcn_mfma_f32_16x16x32_bf16(a1, b3r, sre, 0, 0, 0);
            sre = __builtin_amdgcn_mfma_f32_16x16x32_bf16(a2, b2r, sre, 0, 0, 0);
            sre = __builtin_amdgcn_mfma_f32_16x16x32_bf16(a3, b1r, sre, 0, 0, 0);
            floatx4 sim = __builtin_amdgcn_mfma_f32_16x16x32_bf16(a1, b1i, FZ, 0, 0, 0);
            sim = __builtin_amdgcn_mfma_f32_16x16x32_bf16(a1, b2i, sim, 0, 0, 0);
            sim = __builtin_amdgcn_mfma_f32_16x16x32_bf16(a2, b1i, sim, 0, 0, 0);
            sim = __builtin_amdgcn_mfma_f32_16x16x32_bf16(a1, b3i, sim, 0, 0, 0);
            sim = __builtin_amdgcn_mfma_f32_16x16x32_bf16(a2, b2i, sim, 0, 0, 0);
            sim = __builtin_amdgcn_mfma_f32_16x16x32_bf16(a3, b1i, sim, 0, 0, 0);
            #pragma unroll
            for (int r = 0; r < 4; ++r) {
                float xr = sre[r], xi = sim[r];
                float p = __expf(xr - mA[r]);
                float rr = sqrtf(xr * xr + xi * xi);
                float t = p / rr;
                float wr = (rr > 0.f) ? xr * t : p;
                float wi = (rr > 0.f) ? xi * t : 0.f;
                PR[(qd * 4 + r) * 36 + s2 * 16 + lr] = wr;
                PI[(qd * 4 + r) * 36 + s2 * 16 + lr] = wi;
            }
        }
        asm volatile("s_waitcnt lgkmcnt(0)" ::: "memory");
        __builtin_amdgcn_sched_barrier(0);
        float4 r0 = *(const float4*)&PR[lr * 36 + qd * 8];
        float4 r1 = *(const float4*)&PR[lr * 36 + qd * 8 + 4];
        float4 i0 = *(const float4*)&PI[lr * 36 + qd * 8];
        float4 i1 = *(const float4*)&PI[lr * 36 + qd * 8 + 4];
        short4 ha, la, hb, lb;
        split4s(r0.x, r0.y, r0.z, r0.w, ha, la);
        split4s(r1.x, r1.y, r1.z, r1.w, hb, lb);
        short8v wrh = pack8(ha, hb), wrl = pack8(la, lb);
        split4s(i0.x, i0.y, i0.z, i0.w, ha, la);
        split4s(i1.x, i1.y, i1.z, i1.w, hb, lb);
        short8v wih = pack8(ha, hb), wil = pack8(la, lb);
        short8v wihN = negbf(wih), wilN = negbf(wil);
        short8v vrh = *(const short8v*)&vrhB[tt + qd * 8];
        short8v vrl = *(const short8v*)&vrlB[tt + qd * 8];
        short8v vih = *(const short8v*)&vihB[tt + qd * 8];
        short8v vil = *(const short8v*)&vilB[tt + qd * 8];
        accR = __builtin_amdgcn_mfma_f32_16x16x32_bf16(wrh, vrh, accR, 0, 0, 0);
        accR = __builtin_amdgcn_mfma_f32_16x16x32_bf16(wrh, vrl, accR, 0, 0, 0);
        accR = __builtin_amdgcn_mfma_f32_16x16x32_bf16(wrl, vrh, accR, 0, 0, 0);
        accR = __builtin_amdgcn_mfma_f32_16x16x32_bf16(wihN, vih, accR, 0, 0, 0);
        accR = __builtin_amdgcn_mfma_f32_16x16x32_bf16(wihN, vil, accR, 0, 0, 0);
        accR = __builtin_amdgcn_mfma_f32_16x16x32_bf16(wilN, vih, accR, 0, 0, 0);
        accI = __builtin_amdgcn_mfma_f32_16x16x32_bf16(wrh, vih, accI, 0, 0, 0);
        accI = __builtin_amdgcn_mfma_f32_16x16x32_bf16(wrh, vil, accI, 0, 0, 0);
        accI = __builtin_amdgcn_mfma_f32_16x16x32_bf16(wrl, vih, accI, 0, 0, 0);
        accI = __builtin_amdgcn_mfma_f32_16x16x32_bf16(wih, vrh, accI, 0, 0, 0);
        accI = __builtin_amdgcn_mfma_f32_16x16x32_bf16(wih, vrl, accI, 0, 0, 0);
        accI = __builtin_amdgcn_mfma_f32_16x16x32_bf16(wil, vrh, accI, 0, 0, 0);
    }
    size_t ob = ((size_t)b * 2048 + rowbase + qd * 4) * 16 + lr;
    #pragma unroll
    for (int r = 0; r < 4; ++r) {
        atomicAdd(&OFr[ob + (size_t)r * 16], accR[r] * liA[r]);
        atomicAdd(&OFi[ob + (size_t)r * 16], accI[r] * liA[r]);
    }
}

// ---------------------------------------------------------------------------
// MHA over L=3 via rank-17 bilinear forms -> MO (4096, 3072). grid (16,16).
// ---------------------------------------------------------------------------
__launch_bounds__(256)
__global__ void mha_o(const float* __restrict__ R0, const float* __restrict__ R1,
                      const float* __restrict__ R2, const float* __restrict__ Pt,
                      const float* __restrict__ Mten, float* __restrict__ MO)
{
    const int tid = threadIdx.x;
    const int p = blockIdx.x * 256 + tid;
    const int h = blockIdx.y;
    __shared__ float sPv[3 * 64 * 20];
    __shared__ float sM[9 * 17 * 20];
    for (int lin = tid; lin < 3264; lin += 256) {
        int mm = lin / 1088, rem = lin % 1088;
        int rr = rem / 17, a = rem % 17;
        sPv[(mm * 64 + rr) * 20 + a] = Pt[mm * 52224 + (size_t)(2048 + h * 64 + rr) * 17 + a];
    }
    for (int lin = tid; lin < 2601; lin += 256) {
        int lm = lin / 289, rem = lin % 289;
        int a = rem / 17, bq = rem % 17;
        sM[lm * 340 + a * 20 + bq] = Mten[(size_t)h * 2601 + lin];
    }
    __syncthreads();
    float R[3][16];
    float4 R4[3][4];
    #pragma unroll
    for (int j = 0; j < 4; ++j) {
        R4[0][j] = *(const float4*)(R0 + (size_t)p * 16 + j * 4);
        R4[1][j] = *(const float4*)(R1 + (size_t)p * 16 + j * 4);
        R4[2][j] = *(const float4*)(R2 + (size_t)p * 16 + j * 4);
        *(float4*)&R[0][j * 4] = R4[0][j];
        *(float4*)&R[1][j * 4] = R4[1][j];
        *(float4*)&R[2][j * 4] = R4[2][j];
    }
    float w[3][3];
    #pragma unroll
    for (int l = 0; l < 3; ++l) {
        float sc[3];
        #pragma unroll
        for (int mm = 0; mm < 3; ++mm) {
            const float* Mp = &sM[(l * 3 + mm) * 340];
            float s = 0.f;
            #pragma unroll
            for (int a = 0; a < 17; ++a) {
                const float* mr = Mp + a * 20;
                float4 m0 = *(const float4*)(mr), m1 = *(const float4*)(mr + 4);
                float4 m2 = *(const float4*)(mr + 8), m3 = *(const float4*)(mr + 12);
                float t = mr[16];
                t = fmaf(m0.x, R4[mm][0].x, t); t = fmaf(m0.y, R4[mm][0].y, t);
                t = fmaf(m0.z, R4[mm][0].z, t); t = fmaf(m0.w, R4[mm][0].w, t);
                t = fmaf(m1.x, R4[mm][1].x, t); t = fmaf(m1.y, R4[mm][1].y, t);
                t = fmaf(m1.z, R4[mm][1].z, t); t = fmaf(m1.w, R4[mm][1].w, t);
                t = fmaf(m2.x, R4[mm][2].x, t); t = fmaf(m2.y, R4[mm][2].y, t);
                t = fmaf(m2.z, R4[mm][2].z, t); t = fmaf(m2.w, R4[mm][2].w, t);
                t = fmaf(m3.x, R4[mm][3].x, t); t = fmaf(m3.y, R4[mm][3].y, t);
                t = fmaf(m3.z, R4[mm][3].z, t); t = fmaf(m3.w, R4[mm][3].w, t);
                float ra = (a < 16) ? R[l][a] : 1.f;
                s = fmaf(ra, t, s);
            }
            sc[mm] = s;
        }
        float mx = fmaxf(sc[0], fmaxf(sc[1], sc[2]));
        float e0 = expf(sc[0] - mx), e1 = expf(sc[1] - mx), e2 = expf(sc[2] - mx);
        float inv = 1.f / (e0 + e1 + e2);
        w[l][0] = e0 * inv; w[l][1] = e1 * inv; w[l][2] = e2 * inv;
    }
    #pragma unroll
    for (int d4 = 0; d4 < 16; ++d4) {
        float4 vm[3];
        #pragma unroll
        for (int mm = 0; mm < 3; ++mm) {
            float vx[4];
            #pragma unroll
            for (int r = 0; r < 4; ++r) {
                const float* pv = &sPv[(mm * 64 + d4 * 4 + r) * 20];
                float4 p0 = *(const float4*)(pv), p1 = *(const float4*)(pv + 4);
                float4 p2 = *(const float4*)(pv + 8), p3 = *(const float4*)(pv + 12);
                float t = pv[16];
                t = fmaf(R4[mm][0].x, p0.x, t); t = fmaf(R4[mm][0].y, p0.y, t);
                t = fmaf(R4[mm][0].z, p0.z, t); t = fmaf(R4[mm][0].w, p0.w, t);
                t = fmaf(R4[mm][1].x, p1.x, t); t = fmaf(R4[mm][1].y, p1.y, t);
                t = fmaf(R4[mm][1].z, p1.z, t); t = fmaf(R4[mm][1].w, p1.w, t);
                t = fmaf(R4[mm][2].x, p2.x, t); t = fmaf(R4[mm][2].y, p2.y, t);
                t = fmaf(R4[mm][2].z, p2.z, t); t = fmaf(R4[mm][2].w, p2.w, t);
                t = fmaf(R4[mm][3].x, p3.x, t); t = fmaf(R4[mm][3].y, p3.y, t);
                t = fmaf(R4[mm][3].w, p3.w, t); t = fmaf(R4[mm][3].z, p3.z, t);
                vx[r] = t;
            }
            vm[mm] = (float4){vx[0], vx[1], vx[2], vx[3]};
        }
        #pragma unroll
        for (int l = 0; l < 3; ++l) {
            float4 o4;
            o4.x = w[l][0] * vm[0].x + w[l][1] * vm[1].x + w[l][2] * vm[2].x;
            o4.y = w[l][0] * vm[0].y + w[l][1] * vm[1].y + w[l][2] * vm[2].y;
            o4.z = w[l][0] * vm[0].z + w[l][1] * vm[1].z + w[l][2] * vm[2].z;
            o4.w = w[l][0] * vm[0].w + w[l][1] * vm[1].w + w[l][2] * vm[2].w;
            *(float4*)(MO + (size_t)p * 3072 + l * 1024 + h * 64 + d4 * 4) = o4;
        }
    }
}

// ---------------------------------------------------------------------------
// Host
// ---------------------------------------------------------------------------
extern "C" void kernel_launch(void* const* d_in, const int* in_sizes, int n_in,
                              void* d_out, int out_size, void* d_ws, size_t ws_size,
                              hipStream_t stream)
{
    const float* query = (const float*)d_in[0];
    const float* Wp[3] = {(const float*)d_in[1], (const float*)d_in[6],  (const float*)d_in[11]};
    const float* bp[3] = {(const float*)d_in[2], (const float*)d_in[7],  (const float*)d_in[12]};
    const float* Wc[3] = {(const float*)d_in[3], (const float*)d_in[8],  (const float*)d_in[13]};
    const float* bc[3] = {(const float*)d_in[4], (const float*)d_in[9],  (const float*)d_in[14]};
    const float* Fp[3] = {(const float*)d_in[5], (const float*)d_in[10], (const float*)d_in[15]};
    const float* mha_iw = (const float*)d_in[16];
    const float* mha_ib = (const float*)d_in[17];
    const float* mha_ow = (const float*)d_in[18];
    const float* mha_ob = (const float*)d_in[19];
    const float* fus_W  = (const float*)d_in[20];
    const float* fus_b  = (const float*)d_in[21];
    float* out = (float*)d_out;
    float* ws = (float*)d_ws;

    size_t off = 0;
    auto alloc = [&](size_t n) { float* p = ws + off; off += n; return p; };
    float* MAT0 = alloc(4194304);
    float* MAT1 = alloc(4194304);
    float* DCTD = alloc(4194304);
    float* DCTI = alloc(4194304);
    float* MO   = alloc((size_t)4096 * 3072);
    float* FTb  = alloc((size_t)1024 * 3072);
    float* OWT  = alloc((size_t)1024 * 1024);
    float* WpT  = alloc(3145728);
    float* fwT  = alloc(49152);
    float* W2cat = alloc(147456);
    float* ubv  = alloc(256);
    float* Gm   = alloc(1024);
    float* W3cat = alloc(147456);     // contiguous init region start
    float* Ucat = alloc(589824);
    float* Tfr  = alloc(196608);
    float* Tfi  = alloc(196608);
    float* Tc   = alloc(196608);
    float* Rf   = alloc(65536);
    float* Rc   = alloc(65536);       // init region end
    float* Tw   = alloc(196608);
    float* chFr = alloc(65536); float* chFi = alloc(65536);
    float* QpFr = alloc(65536); float* QpFi = alloc(65536);
    float* chW  = alloc(65536); float* QpW  = alloc(65536);
    float* chC  = alloc(65536); float* QpC  = alloc(65536);
    float* OFr  = alloc(65536); float* OFi  = alloc(65536);
    float* Ow   = alloc(65536); float* Oc   = alloc(65536);
    float* Pt   = alloc(156672);
    float* Mten = alloc(41616);
    float* ybv  = alloc(1024);
    if (ws_size < off * sizeof(float)) return;

    // ---- flash MFMA operand pool: aliased into WpT (dead after skmfma #1).
    // Split-3 layout. Total 1,368,064 floats <= 3,145,728 (WpT).
    size_t poff = 0;
    auto palloc = [&](size_t n) { float* p = WpT + poff; poff += n; return p; };
    float* AqW  = palloc(98304);
    float* KsW  = palloc(98304);
    float* AqC  = palloc(98304);
    float* KsC  = palloc(98304);
    float* VtWH = palloc(32768); float* VtWL = palloc(32768);
    float* VtCH = palloc(32768); float* VtCL = palloc(32768);
    float* AqF  = palloc(196608);
    float* BreF = palloc(196608);
    float* BimF = palloc(196608);
    float* VtFrH = palloc(32768); float* VtFrL = palloc(32768);
    float* VtFiH = palloc(32768); float* VtFiL = palloc(32768);
    float* Mpart = palloc(49152); float* Lpart = palloc(49152);
    float* MrowA = palloc(12288); float* LinvA = palloc(12288);

    float* Uf = Ucat, *Uw = Ucat + 196608, *Uc = Ucat + 2 * 196608;
    const long SE48 = 2048 * 48, SE16 = 2048 * 16;

    // ---- prep ----
    build_w2<<<dim3(576), dim3(256), 0, stream>>>(Wc[0], Wc[1], Wc[2], W2cat);
    prep_fw_G<<<dim3(3), dim3(256), 0, stream>>>(Fp[0], Fp[1], Fp[2], fwT, Gm);
    build_ub2<<<dim3(3), dim3(256), 0, stream>>>(bp[0], bp[1], bp[2], W2cat, ubv);
    build_yb2<<<dim3(256), dim3(256), 0, stream>>>(mha_ob, fus_W, fus_b, ybv);
    gen_trig<<<dim3(32768), dim3(256), 0, stream>>>(MAT0, MAT1, DCTD, DCTI);
    transpose_wp3<<<dim3(32, 32, 3), dim3(256), 0, stream>>>(Wp[0], Wp[1], Wp[2], WpT);
    init_all<<<dim3(34980), dim3(256), 0, stream>>>(W3cat, ubv, Pt, FTb, out, ybv);

    // ---- skinny MFMA products ----
    // W3_d = Wp_d^T @ W2_d
    skmfma<48, 0><<<dim3(16, 1, 6), dim3(256), 0, stream>>>(
        WpT, nullptr, W2cat, nullptr, W3cat, nullptr,
        1024, 1024, 48, 48, 1048576, 49152, 49152, 1.f, 2);
    // U_d = query @ W3_d (+ub preloaded)
    skmfma<48, 0><<<dim3(64, 1, 6), dim3(256), 0, stream>>>(
        query, nullptr, W3cat, nullptr, Ucat, nullptr,
        1024, 1024, 48, 48, 0, 49152, 196608, 1.f, 2);
    // Fourier fwd: Tfr = MAT0@Uf, Tfi = MAT1@Uf (dual-A)
    skmfma<48, 1><<<dim3(32, 1, 8), dim3(256), 0, stream>>>(
        MAT0, MAT1, Uf, nullptr, Tfr, Tfi,
        2048, 2048, 48, 48, 0, SE48, SE48, 1.f, 4);
    // DCT fwd: Tc = DCTD@Uc
    skmfma<48, 0><<<dim3(32, 1, 8), dim3(256), 0, stream>>>(
        DCTD, nullptr, Uc, nullptr, Tc, nullptr,
        2048, 2048, 48, 48, 0, SE48, SE48, 1.f, 4);

    // Haar pyramid
    haar_all<<<dim3(12, 2), dim3(256), 0, stream>>>(Uw, Tw);

    // conv collapse + G fold (all domains)
    conv_all<<<dim3(32, 2, 3), dim3(256), 0, stream>>>(
        Tfr, Tfi, Tw, Tc, Gm, bc[0], bc[1], bc[2],
        chFr, chFi, chW, chC, QpFr, QpFi, QpW, QpC);

    // ---- MFMA flash attention (stats + merge + PV) ----
    prep_flash<<<dim3(8, 2, 3), dim3(256), 0, stream>>>(
        QpFr, QpFi, chFr, chFi, QpW, chW, QpC, chC,
        (short*)AqF, (short*)BreF, (short*)BimF,
        (short*)VtFrH, (short*)VtFrL, (short*)VtFiH, (short*)VtFiL,
        (short*)AqW, (short*)KsW, (short*)VtWH, (short*)VtWL,
        (short*)AqC, (short*)KsC, (short*)VtCH, (short*)VtCL);
    flash_stats<<<dim3(32, 4, 6), dim3(256), 0, stream>>>(
        (const short*)AqF, (const short*)BreF,
        (const short*)AqW, (const short*)KsW,
        (const short*)AqC, (const short*)KsC, Mpart, Lpart);
    flash_merge<<<dim3(1072), dim3(256), 0, stream>>>(Mpart, Lpart, MrowA, LinvA, OFr);
    flash_pv<<<dim3(32, 4, 6), dim3(256), 0, stream>>>(
        (const short*)AqF, (const short*)BreF, (const short*)BimF,
        (const short*)VtFrH, (const short*)VtFrL, (const short*)VtFiH, (const short*)VtFiL,
        (const short*)AqW, (const short*)KsW, (const short*)VtWH, (const short*)VtWL,
        (const short*)AqC, (const short*)KsC, (const short*)VtCH, (const short*)VtCL,
        MrowA, LinvA, OFr, OFi, Ow, Oc);

    // Fourier inv: Rf = (1/S)(MAT0@OFr + MAT1@OFi)  (dual-A dual-B)
    skmfma<16, 2><<<dim3(32, 1, 8), dim3(256), 0, stream>>>(
        MAT0, MAT1, OFr, OFi, Rf, nullptr,
        2048, 2048, 16, 16, 0, SE16, SE16, 1.f / 2048.f, 4);
    // DCT inv: Rc = DCTI@Oc
    skmfma<16, 0><<<dim3(32, 1, 8), dim3(256), 0, stream>>>(
        DCTI, nullptr, Oc, nullptr, Rc, nullptr,
        2048, 2048, 16, 16, 0, SE16, SE16, 1.f, 4);
    // Pt_l = mha_iw @ fwT_l (cols 0..15 of pitch-17 Pt)
    skmfma<16, 0><<<dim3(48, 1, 6), dim3(256), 0, stream>>>(
        mha_iw, nullptr, fwT, nullptr, Pt, nullptr,
        1024, 1024, 16, 17, 0, 16384, 52224, 1.f, 2);

    ib_append<<<dim3(36), dim3(256), 0, stream>>>(mha_ib, Pt);
    build_M<<<dim3(144), dim3(256), 0, stream>>>(Pt, Mten);

    // MHA core -> MO (4096, 3072)
    mha_o<<<dim3(16, 16), dim3(256), 0, stream>>>(Rf, Ow, Rc, Pt, Mten, MO);

    // FT_l = fusW_l @ ow  (atomic K-split, FTb pre-zeroed)
    transpose_k<<<dim3(32, 32), dim3(256), 0, stream>>>(mha_ow, OWT, 1024, 1024);
    gemm_at<<<dim3(8, 8, 6), dim3(256), 0, stream>>>(
        fus_W, OWT, FTb, 1024, 3072, 1024, 3072, 1024, 0, 1024, 1.f, 2);

    // out = MO @ FTb^T + yb  (out pre-initialized with yb; atomic K-split)
    gemm_at<<<dim3(8, 32, 2), dim3(256), 0, stream>>>(
        MO, FTb, out, 3072, 3072, 3072, 1024, 0, 0, 0, 1.f, 2);
}